// Round 9
// baseline (119.137 us; speedup 1.0000x reference)
//
#include <hip/hip_runtime.h>
#include <math.h>

// Problem constants
#define NB 4
#define NC 2048
#define NH 8
#define NK 128

// exp2-domain logit scale: log2(e)/sqrt(128)
#define A2SCALE (1.4426950408889634f * 0.08838834764831845f)

typedef __attribute__((ext_vector_type(8))) short bf16x8;
typedef __attribute__((ext_vector_type(4))) float f32x4;

// ---------------- ws layout (float offsets) ----------------
// wspart [4][2048]        @ 0        (8192)   e-quarter partials of wq/wk sums
// W2     [8][128][128]    @ 8192     (131072) f32
// qs     [32][2048]       @ 139264
// ks     [32][2048]       @ 204800
// u(bf16)[32][64ig][8nt][64lane][8j] @ 270336 (8.39M ushort)
#define OFF_W2  8192
#define OFF_QS  139264
#define OFF_KS  204800
#define OFF_U   270336

__device__ static inline float exp2_hw(float x) {
#if __has_builtin(__builtin_amdgcn_exp2f)
    return __builtin_amdgcn_exp2f(x);
#else
    float r;
    asm volatile("v_exp_f32 %0, %1\n\ts_nop 1" : "=v"(r) : "v"(x));
    return r;
#endif
}

// pack 2 f32 -> u32 of 2 bf16 (RNE), low half = first arg
__device__ static inline unsigned cvtpk(float lo, float hi) {
    unsigned r;
    asm("v_cvt_pk_bf16_f32 %0, %1, %2" : "=v"(r) : "v"(lo), "v"(hi));
    return r;
}

__device__ static inline bf16x8 pack8(float4 a, float4 b) {
    union { unsigned u[4]; bf16x8 v; } r;
    r.u[0] = cvtpk(a.x, a.y);
    r.u[1] = cvtpk(a.z, a.w);
    r.u[2] = cvtpk(b.x, b.y);
    r.u[3] = cvtpk(b.z, b.w);
    return r.v;
}

// 8 exps of (a*k + negM) packed to a bf16x8 A-fragment; accumulates sum in z
__device__ static inline bf16x8 pexp8s(float4 ka, float4 kb, float a, float negM,
                                       float& z) {
    float e0 = exp2_hw(fmaf(a, ka.x, negM));
    float e1 = exp2_hw(fmaf(a, ka.y, negM));
    float e2 = exp2_hw(fmaf(a, ka.z, negM));
    float e3 = exp2_hw(fmaf(a, ka.w, negM));
    float e4 = exp2_hw(fmaf(a, kb.x, negM));
    float e5 = exp2_hw(fmaf(a, kb.y, negM));
    float e6 = exp2_hw(fmaf(a, kb.z, negM));
    float e7 = exp2_hw(fmaf(a, kb.w, negM));
    z += ((e0 + e1) + (e2 + e3)) + ((e4 + e5) + (e6 + e7));
    union { unsigned u[4]; bf16x8 v; } r;
    r.u[0] = cvtpk(e0, e1);
    r.u[1] = cvtpk(e2, e3);
    r.u[2] = cvtpk(e4, e5);
    r.u[3] = cvtpk(e6, e7);
    return r.v;
}

// wspart[eq][which*1024+h*128+m] = sum_{e in eq*32..+32} W[h*128+e][m]
// Also initializes y = bias.  grid 64 x 256   (R8-identical)
__global__ __launch_bounds__(256) void k_wsum(const float* __restrict__ Wq,
                                              const float* __restrict__ Wk,
                                              float* __restrict__ wspart,
                                              const float* __restrict__ bo,
                                              float* __restrict__ y) {
    int blk = blockIdx.x;
    int which = blk >> 5, h = (blk >> 2) & 7, eq = blk & 3;
    const float* W = which ? Wk : Wq;
    int m = threadIdx.x & 127, part = threadIdx.x >> 7;
    const float* base = W + (h * 128 + eq * 32 + part * 16) * 128 + m;
    float s = 0.f;
#pragma unroll
    for (int e = 0; e < 16; ++e) s += base[e * 128];
    __shared__ float sp[128];
    if (part) sp[m] = s;
    __syncthreads();
    if (!part) wspart[eq * 2048 + which * 1024 + h * 128 + m] = s + sp[m];

    // y init: 262144 float4s over 64 blocks = 4096/block
    int base4 = blk * 4096 + threadIdx.x;
#pragma unroll
    for (int q = 0; q < 16; ++q) {
        int id = base4 + q * 256;
        ((float4*)y)[id] = ((const float4*)bo)[id & 31];
    }
}

// W2[h][kk][m] = sum_e Wv[h*128+e][m] * Wo[kk][h*128+e].  grid 1024 x 128
// (R8-identical)
__global__ __launch_bounds__(128) void k_w2(const float* __restrict__ Wv,
                                            const float* __restrict__ Wo,
                                            float* __restrict__ W2) {
    int h = blockIdx.x >> 7, kk = blockIdx.x & 127;
    __shared__ float wo_s[128];
    int m = threadIdx.x;
    wo_s[m] = Wo[kk * 1024 + h * 128 + m];
    __syncthreads();
    const float* base = Wv + (h * 128) * 128 + m;
    float s = 0.f;
#pragma unroll 4
    for (int e = 0; e < 128; ++e) s += base[e * 128] * wo_s[e];
    W2[(h * 128 + kk) * 128 + m] = s;
}

// qs[bh][t], ks[bh][t].  grid 256 x 256 (32 rows per block)  (R8-identical)
__global__ __launch_bounds__(256) void k_qsks(const float* __restrict__ x,
                                              const float* __restrict__ wspart,
                                              float* __restrict__ qs,
                                              float* __restrict__ ks) {
    __shared__ float xs[32][129];
    __shared__ float wsum[2048];
    int tid = threadIdx.x;
    for (int j = tid; j < 2048; j += 256)
        wsum[j] = wspart[j] + wspart[2048 + j] + wspart[4096 + j] + wspart[6144 + j];
    int row0 = blockIdx.x * 32;
    for (int j = tid; j < 32 * 128; j += 256) {
        int r = j >> 7, m = j & 127;
        xs[r][m] = x[(size_t)(row0 + r) * 128 + m];
    }
    __syncthreads();
#pragma unroll
    for (int jj = 0; jj < 2; ++jj) {
        int o = tid + 256 * jj;
        int r = o & 31;
        int q = o >> 5;
        int which = q >> 3, h = q & 7;
        const float* wrow = &wsum[which * 1024 + h * 128];
        float s = 0.f;
#pragma unroll 4
        for (int m = 0; m < 128; ++m) s += xs[r][m] * wrow[m];
        int row = row0 + r, b = row >> 11, t = row & 2047;
        float* dst = which ? ks : qs;
        dst[(b * 8 + h) * 2048 + t] = s;
    }
}

// u[bh][i][kk] = sum_m x[b][i][m] * W2[h][kk][m]  via bf16 MFMA, register GEMM.
// Output in u B-frag layout [bh][ig=i>>5][nt=kk>>4][lane][j].  grid 512 x 256
// blockIdx XCD-aligned with k_attn: block (bh,it) runs on XCD = bh>>2, so the
// u slice is written through the SAME XCD L2 that k_attn reads it from.
__global__ __launch_bounds__(256) void k_ugemm(const float* __restrict__ x,
                                               const float* __restrict__ W2,
                                               unsigned short* __restrict__ u16) {
    int L = blockIdx.x;
    int xcd = L & 7, s = L >> 3;          // s in 0..63
    int bh = xcd * 4 + (s >> 4);          // bh>>2 == xcd  (matches k_attn)
    int it = s & 15;
    int b = bh >> 3, h = bh & 7;
    int tid = threadIdx.x;
    int lane = tid & 63, wid = tid >> 6;
    int wr = wid >> 1, wc = wid & 1;
    int l15 = lane & 15, l4 = lane >> 4;

    const float* xb = x + (size_t)(b * 2048 + it * 128) * 128;
    const float* w2h = W2 + h * 16384;

    f32x4 acc[4][4];
#pragma unroll
    for (int m = 0; m < 4; ++m)
#pragma unroll
        for (int n = 0; n < 4; ++n) acc[m][n] = (f32x4)0.f;

#pragma unroll
    for (int mg = 0; mg < 4; ++mg) {
        bf16x8 af[4], bfr[4];
#pragma unroll
        for (int m = 0; m < 4; ++m) {
            const float* src = xb + (wr * 64 + m * 16 + l15) * 128 + mg * 32 + l4 * 8;
            af[m] = pack8(*(const float4*)src, *(const float4*)(src + 4));
        }
#pragma unroll
        for (int n = 0; n < 4; ++n) {
            const float* src = w2h + (wc * 64 + n * 16 + l15) * 128 + mg * 32 + l4 * 8;
            bfr[n] = pack8(*(const float4*)src, *(const float4*)(src + 4));
        }
#pragma unroll
        for (int m = 0; m < 4; ++m)
#pragma unroll
            for (int n = 0; n < 4; ++n)
                acc[m][n] = __builtin_amdgcn_mfma_f32_16x16x32_bf16(
                    af[m], bfr[n], acc[m][n], 0, 0, 0);
    }

    // transpose acc -> u B-frag layout through LDS (32 KB)
    __shared__ unsigned u_sh[8192];
#pragma unroll
    for (int m = 0; m < 4; ++m) {
        int i_base = wr * 64 + m * 16 + l4 * 4;
        int ig = i_base >> 5;
        int lg = 16 * ((i_base >> 3) & 3);
        int jp = (i_base & 7) >> 1;          // 0 or 2
#pragma unroll
        for (int n = 0; n < 4; ++n) {
            int kk = wc * 64 + n * 16 + l15;
            int lp = (kk & 15) + lg;
            int idx = ((ig * 8 + (kk >> 4)) * 64 + lp) * 4 + jp;
            uint2 w;
            w.x = cvtpk(acc[m][n][0], acc[m][n][1]);
            w.y = cvtpk(acc[m][n][2], acc[m][n][3]);
            *(uint2*)&u_sh[idx] = w;
        }
    }
    __syncthreads();
    unsigned short* ub = u16 + ((size_t)(b * 8 + h) * 64 + it * 4) * 4096;
#pragma unroll
    for (int q = 0; q < 8; ++q)
        ((uint4*)ub)[tid + q * 256] = ((const uint4*)u_sh)[tid + q * 256];
}

// ---- attention: y[b][t][kk] += (1/z_t) sum_i P[t,i] * u[i,kk] ----
// grid 512 x 256: 32 bh x 16 t-tiles of 128. Waves 2x2: wr = t-half (64 rows),
// wc = kk-half (64 cols). u read straight into registers (B-frag order) with
// compiler-managed vmcnt -- NO LDS staging, NO barriers in the main loop.
// P per-lane in registers; z per-lane f32 + shfl reduce.
__global__ __launch_bounds__(256, 2) void k_attn(const float* __restrict__ qs,
                                                 const float* __restrict__ ks,
                                                 const unsigned short* __restrict__ ub,
                                                 float* __restrict__ y) {
    int L = blockIdx.x;
    int xcd = L & 7, slot = L >> 3;
    int bh = xcd * 4 + (slot >> 4);   // 4 bh per XCD; u slice L2-resident
    int tt = slot & 15;
    int b = bh >> 3;
    int t0 = tt * 128;
    int tid = threadIdx.x;
    int lane = tid & 63, wid = tid >> 6;
    int wr = wid >> 1, wc = wid & 1;
    int l15 = lane & 15, l4 = lane >> 4;

    __shared__ float kss[2048];   // 8 KB
    __shared__ float zs[128];
    __shared__ float red[8];

    for (int j = tid; j < 512; j += 256)
        ((float4*)kss)[j] = ((const float4*)(ks + bh * 2048))[j];
    // this lane's rows: t0 + wr*64 + m*16 + l15, m = 0..3
    float a[4], negM[4], z[4];
#pragma unroll
    for (int m = 0; m < 4; ++m)
        a[m] = qs[bh * 2048 + t0 + wr * 64 + m * 16 + l15] * A2SCALE;
    __syncthreads();

    // block-wide min/max of kss
    float mn = 1e30f, mx = -1e30f;
    {
        const float4* ka = (const float4*)kss;
#pragma unroll
        for (int jj = 0; jj < 2; ++jj) {
            float4 v = ka[tid + jj * 256];
            mn = fminf(mn, fminf(fminf(v.x, v.y), fminf(v.z, v.w)));
            mx = fmaxf(mx, fmaxf(fmaxf(v.x, v.y), fmaxf(v.z, v.w)));
        }
#pragma unroll
        for (int off = 32; off; off >>= 1) {
            mn = fminf(mn, __shfl_xor(mn, off));
            mx = fmaxf(mx, __shfl_xor(mx, off));
        }
        if (!lane) { red[wid] = mn; red[4 + wid] = mx; }
    }
    __syncthreads();
    mn = fminf(fminf(red[0], red[1]), fminf(red[2], red[3]));
    mx = fmaxf(fmaxf(red[4], red[5]), fmaxf(red[6], red[7]));
#pragma unroll
    for (int m = 0; m < 4; ++m) {
        negM[m] = -(a[m] > 0.f ? a[m] * mx : a[m] * mn);   // exact row max
        z[m] = 0.f;
    }

    const unsigned short* gub = ub + (size_t)bh * 262144;

    f32x4 acc[4][4];
#pragma unroll
    for (int m = 0; m < 4; ++m)
#pragma unroll
        for (int n = 0; n < 4; ++n) acc[m][n] = (f32x4)0.f;

#pragma unroll 2
    for (int ic = 0; ic < 2048; ic += 32) {
        // this wave's u fragments for its kk-half: nt = wc*4 + n
        const unsigned short* ubase =
            gub + ((size_t)(ic >> 5) * 8 + wc * 4) * 512 + lane * 8;
        bf16x8 uf[4];
#pragma unroll
        for (int n = 0; n < 4; ++n)
            uf[n] = *(const bf16x8*)(ubase + n * 512);

        // per-lane P A-fragments: row = l15 (per m-group), k = ic + l4*8 + j
        float4 ka = *(const float4*)&kss[ic + l4 * 8];
        float4 kb = *(const float4*)&kss[ic + l4 * 8 + 4];
        bf16x8 pf[4];
#pragma unroll
        for (int m = 0; m < 4; ++m)
            pf[m] = pexp8s(ka, kb, a[m], negM[m], z[m]);

#pragma unroll
        for (int m = 0; m < 4; ++m)
#pragma unroll
            for (int n = 0; n < 4; ++n)
                acc[m][n] = __builtin_amdgcn_mfma_f32_16x16x32_bf16(
                    pf[m], uf[n], acc[m][n], 0, 0, 0);
    }

    // z: sum the 4 k-slices (over l4) -> lanes with same l15 share row-z
#pragma unroll
    for (int m = 0; m < 4; ++m) {
        z[m] += __shfl_xor(z[m], 16);
        z[m] += __shfl_xor(z[m], 32);
    }
    if (wc == 0 && l4 == 0) {
#pragma unroll
        for (int m = 0; m < 4; ++m) zs[wr * 64 + m * 16 + l15] = z[m];
    }
    __syncthreads();

    // epilogue: C/D layout col=lane&15, row=(lane>>4)*4+reg
#pragma unroll
    for (int m = 0; m < 4; ++m) {
#pragma unroll
        for (int r = 0; r < 4; ++r) {
            int tl = wr * 64 + m * 16 + l4 * 4 + r;
            float zinv = 1.f / zs[tl];
            float* yrow = y + ((size_t)b * 2048 + t0 + tl) * 128;
#pragma unroll
            for (int n = 0; n < 4; ++n)
                atomicAdd(&yrow[wc * 64 + n * 16 + l15], acc[m][n][r] * zinv);
        }
    }
}

extern "C" void kernel_launch(void* const* d_in, const int* in_sizes, int n_in,
                              void* d_out, int out_size, void* d_ws, size_t ws_size,
                              hipStream_t stream) {
    const float* x  = (const float*)d_in[0];
    const float* Wq = (const float*)d_in[1];
    const float* Wk = (const float*)d_in[2];
    const float* Wv = (const float*)d_in[3];
    const float* Wo = (const float*)d_in[4];
    const float* bo = (const float*)d_in[5];
    float* y  = (float*)d_out;
    float* ws = (float*)d_ws;
    (void)in_sizes; (void)n_in; (void)out_size; (void)ws_size;

    unsigned short* u16 = (unsigned short*)(ws + OFF_U);

    k_wsum<<<64, 256, 0, stream>>>(Wq, Wk, ws, bo, y);
    k_w2<<<1024, 128, 0, stream>>>(Wv, Wo, ws + OFF_W2);
    k_qsks<<<256, 256, 0, stream>>>(x, ws, ws + OFF_QS, ws + OFF_KS);
    k_ugemm<<<512, 256, 0, stream>>>(x, ws + OFF_W2, u16);
    k_attn<<<512, 256, 0, stream>>>(ws + OFF_QS, ws + OFF_KS, u16, y);
}

// Round 10
// 106.178 us; speedup vs baseline: 1.1220x; 1.1220x over previous
//
#include <hip/hip_runtime.h>
#include <math.h>

// Problem constants
#define NB 4
#define NC 2048
#define NH 8
#define NK 128

// exp2-domain logit scale: log2(e)/sqrt(128)
#define A2SCALE (1.4426950408889634f * 0.08838834764831845f)

typedef __attribute__((ext_vector_type(8))) short bf16x8;
typedef __attribute__((ext_vector_type(4))) float f32x4;

// ---------------- ws layout (float offsets) ----------------
// wspart [4][2048]        @ 0        (8192)   e-quarter partials of wq/wk sums
// W2     [8][128][128]    @ 8192     (131072) f32
// qs     [32][2048]       @ 139264
// ks     [32][2048]       @ 204800
// u(bf16)[32][64ig][8nt][64lane][8j] @ 270336 (8.39M ushort)
#define OFF_W2  8192
#define OFF_QS  139264
#define OFF_KS  204800
#define OFF_U   270336

__device__ static inline float exp2_hw(float x) {
#if __has_builtin(__builtin_amdgcn_exp2f)
    return __builtin_amdgcn_exp2f(x);
#else
    float r;
    asm volatile("v_exp_f32 %0, %1\n\ts_nop 1" : "=v"(r) : "v"(x));
    return r;
#endif
}

// pack 2 f32 -> u32 of 2 bf16 (RNE), low half = first arg
__device__ static inline unsigned cvtpk(float lo, float hi) {
    unsigned r;
    asm("v_cvt_pk_bf16_f32 %0, %1, %2" : "=v"(r) : "v"(lo), "v"(hi));
    return r;
}

__device__ static inline bf16x8 pack8(float4 a, float4 b) {
    union { unsigned u[4]; bf16x8 v; } r;
    r.u[0] = cvtpk(a.x, a.y);
    r.u[1] = cvtpk(a.z, a.w);
    r.u[2] = cvtpk(b.x, b.y);
    r.u[3] = cvtpk(b.z, b.w);
    return r.v;
}

// 8 exps of (a*k + negM) packed to a bf16x8 A-fragment; accumulates sum in z
__device__ static inline bf16x8 pexp8s(float4 ka, float4 kb, float a, float negM,
                                       float& z) {
    float e0 = exp2_hw(fmaf(a, ka.x, negM));
    float e1 = exp2_hw(fmaf(a, ka.y, negM));
    float e2 = exp2_hw(fmaf(a, ka.z, negM));
    float e3 = exp2_hw(fmaf(a, ka.w, negM));
    float e4 = exp2_hw(fmaf(a, kb.x, negM));
    float e5 = exp2_hw(fmaf(a, kb.y, negM));
    float e6 = exp2_hw(fmaf(a, kb.z, negM));
    float e7 = exp2_hw(fmaf(a, kb.w, negM));
    z += ((e0 + e1) + (e2 + e3)) + ((e4 + e5) + (e6 + e7));
    union { unsigned u[4]; bf16x8 v; } r;
    r.u[0] = cvtpk(e0, e1);
    r.u[1] = cvtpk(e2, e3);
    r.u[2] = cvtpk(e4, e5);
    r.u[3] = cvtpk(e6, e7);
    return r.v;
}

// wspart[eq][which*1024+h*128+m] = sum_{e in eq*32..+32} W[h*128+e][m]
// Also initializes y = bias.  grid 64 x 256   (unchanged)
__global__ __launch_bounds__(256) void k_wsum(const float* __restrict__ Wq,
                                              const float* __restrict__ Wk,
                                              float* __restrict__ wspart,
                                              const float* __restrict__ bo,
                                              float* __restrict__ y) {
    int blk = blockIdx.x;
    int which = blk >> 5, h = (blk >> 2) & 7, eq = blk & 3;
    const float* W = which ? Wk : Wq;
    int m = threadIdx.x & 127, part = threadIdx.x >> 7;
    const float* base = W + (h * 128 + eq * 32 + part * 16) * 128 + m;
    float s = 0.f;
#pragma unroll
    for (int e = 0; e < 16; ++e) s += base[e * 128];
    __shared__ float sp[128];
    if (part) sp[m] = s;
    __syncthreads();
    if (!part) wspart[eq * 2048 + which * 1024 + h * 128 + m] = s + sp[m];

    // y init: 262144 float4s over 64 blocks = 4096/block
    int base4 = blk * 4096 + threadIdx.x;
#pragma unroll
    for (int q = 0; q < 16; ++q) {
        int id = base4 + q * 256;
        ((float4*)y)[id] = ((const float4*)bo)[id & 31];
    }
}

// W2[h][kk][m] = sum_e Wv[h*128+e][m] * Wo[kk][h*128+e].  grid 1024 x 128
// (unchanged)
__global__ __launch_bounds__(128) void k_w2(const float* __restrict__ Wv,
                                            const float* __restrict__ Wo,
                                            float* __restrict__ W2) {
    int h = blockIdx.x >> 7, kk = blockIdx.x & 127;
    __shared__ float wo_s[128];
    int m = threadIdx.x;
    wo_s[m] = Wo[kk * 1024 + h * 128 + m];
    __syncthreads();
    const float* base = Wv + (h * 128) * 128 + m;
    float s = 0.f;
#pragma unroll 4
    for (int e = 0; e < 128; ++e) s += base[e * 128] * wo_s[e];
    W2[(h * 128 + kk) * 128 + m] = s;
}

// qs[bh][t], ks[bh][t].  grid 256 x 256 (32 rows per block)  (unchanged)
__global__ __launch_bounds__(256) void k_qsks(const float* __restrict__ x,
                                              const float* __restrict__ wspart,
                                              float* __restrict__ qs,
                                              float* __restrict__ ks) {
    __shared__ float xs[32][129];
    __shared__ float wsum[2048];
    int tid = threadIdx.x;
    for (int j = tid; j < 2048; j += 256)
        wsum[j] = wspart[j] + wspart[2048 + j] + wspart[4096 + j] + wspart[6144 + j];
    int row0 = blockIdx.x * 32;
    for (int j = tid; j < 32 * 128; j += 256) {
        int r = j >> 7, m = j & 127;
        xs[r][m] = x[(size_t)(row0 + r) * 128 + m];
    }
    __syncthreads();
#pragma unroll
    for (int jj = 0; jj < 2; ++jj) {
        int o = tid + 256 * jj;
        int r = o & 31;
        int q = o >> 5;
        int which = q >> 3, h = q & 7;
        const float* wrow = &wsum[which * 1024 + h * 128];
        float s = 0.f;
#pragma unroll 4
        for (int m = 0; m < 128; ++m) s += xs[r][m] * wrow[m];
        int row = row0 + r, b = row >> 11, t = row & 2047;
        float* dst = which ? ks : qs;
        dst[(b * 8 + h) * 2048 + t] = s;
    }
}

// u[bh][i][kk] = sum_m x[b][i][m] * W2[h][kk][m]  via bf16 MFMA, register GEMM.
// Output in u B-frag layout [bh][ig=i>>5][nt=kk>>4][lane][j].  grid 512 x 256
// (unchanged, XCD-aligned mapping)
__global__ __launch_bounds__(256) void k_ugemm(const float* __restrict__ x,
                                               const float* __restrict__ W2,
                                               unsigned short* __restrict__ u16) {
    int L = blockIdx.x;
    int xcd = L & 7, s = L >> 3;          // s in 0..63
    int bh = xcd * 4 + (s >> 4);          // bh>>2 == xcd  (matches k_attn)
    int it = s & 15;
    int b = bh >> 3, h = bh & 7;
    int tid = threadIdx.x;
    int lane = tid & 63, wid = tid >> 6;
    int wr = wid >> 1, wc = wid & 1;
    int l15 = lane & 15, l4 = lane >> 4;

    const float* xb = x + (size_t)(b * 2048 + it * 128) * 128;
    const float* w2h = W2 + h * 16384;

    f32x4 acc[4][4];
#pragma unroll
    for (int m = 0; m < 4; ++m)
#pragma unroll
        for (int n = 0; n < 4; ++n) acc[m][n] = (f32x4)0.f;

#pragma unroll
    for (int mg = 0; mg < 4; ++mg) {
        bf16x8 af[4], bfr[4];
#pragma unroll
        for (int m = 0; m < 4; ++m) {
            const float* src = xb + (wr * 64 + m * 16 + l15) * 128 + mg * 32 + l4 * 8;
            af[m] = pack8(*(const float4*)src, *(const float4*)(src + 4));
        }
#pragma unroll
        for (int n = 0; n < 4; ++n) {
            const float* src = w2h + (wc * 64 + n * 16 + l15) * 128 + mg * 32 + l4 * 8;
            bfr[n] = pack8(*(const float4*)src, *(const float4*)(src + 4));
        }
#pragma unroll
        for (int m = 0; m < 4; ++m)
#pragma unroll
            for (int n = 0; n < 4; ++n)
                acc[m][n] = __builtin_amdgcn_mfma_f32_16x16x32_bf16(
                    af[m], bfr[n], acc[m][n], 0, 0, 0);
    }

    // transpose acc -> u B-frag layout through LDS (32 KB)
    __shared__ unsigned u_sh[8192];
#pragma unroll
    for (int m = 0; m < 4; ++m) {
        int i_base = wr * 64 + m * 16 + l4 * 4;
        int ig = i_base >> 5;
        int lg = 16 * ((i_base >> 3) & 3);
        int jp = (i_base & 7) >> 1;          // 0 or 2
#pragma unroll
        for (int n = 0; n < 4; ++n) {
            int kk = wc * 64 + n * 16 + l15;
            int lp = (kk & 15) + lg;
            int idx = ((ig * 8 + (kk >> 4)) * 64 + lp) * 4 + jp;
            uint2 w;
            w.x = cvtpk(acc[m][n][0], acc[m][n][1]);
            w.y = cvtpk(acc[m][n][2], acc[m][n][3]);
            *(uint2*)&u_sh[idx] = w;
        }
    }
    __syncthreads();
    unsigned short* ub = u16 + ((size_t)(b * 8 + h) * 64 + it * 4) * 4096;
#pragma unroll
    for (int q = 0; q < 8; ++q)
        ((uint4*)ub)[tid + q * 256] = ((const uint4*)u_sh)[tid + q * 256];
}

// ---- attention: y[b][t][kk] += (1/z_t) sum_i P[t,i] * u[i,kk] ----
// grid 1024 x 256: 32 bh x 32 t-tiles of 64 (R8-proven shape, 4 blocks/CU).
// THIS ROUND'S ONE CHANGE: deep DMA pipeline (T3/T4) -- 3 LDS buffers,
// counted s_waitcnt vmcnt(2) + raw s_barrier; DMA issued AFTER the barrier
// into buf (N+2)%3, so 2 chunks stay in flight across barriers. The main
// loop contains NO other VMEM ops, so vmcnt counts are exact.
__global__ __launch_bounds__(256, 4) void k_attn(const float* __restrict__ qs,
                                                 const float* __restrict__ ks,
                                                 const unsigned short* __restrict__ ub,
                                                 float* __restrict__ y) {
    int L = blockIdx.x;
    int xcd = L & 7, slot = L >> 3;
    int bh = xcd * 4 + (slot >> 5);   // 4 bh per XCD
    int tt = slot & 31;
    int b = bh >> 3;
    int t0 = tt * 64;
    int tid = threadIdx.x;
    int lane = tid & 63, wid = tid >> 6;
    int l15 = lane & 15, l4 = lane >> 4;

    __shared__ float kss[2048];                           // 8 KB
    __shared__ __align__(16) unsigned short u_l[3][4096]; // 3 x 8 KB
    __shared__ float zs[64];
    __shared__ float red[8];

    for (int j = tid; j < 512; j += 256)
        ((float4*)kss)[j] = ((const float4*)(ks + bh * 2048))[j];
    // this lane's row: t0 + wid*16 + l15 (replicated across l4 groups)
    float a = qs[bh * 2048 + t0 + wid * 16 + l15] * A2SCALE;
    __syncthreads();

    // block-wide min/max of kss
    float mn = 1e30f, mx = -1e30f;
    {
        const float4* ka = (const float4*)kss;
#pragma unroll
        for (int jj = 0; jj < 2; ++jj) {
            float4 v = ka[tid + jj * 256];
            mn = fminf(mn, fminf(fminf(v.x, v.y), fminf(v.z, v.w)));
            mx = fmaxf(mx, fmaxf(fmaxf(v.x, v.y), fmaxf(v.z, v.w)));
        }
#pragma unroll
        for (int off = 32; off; off >>= 1) {
            mn = fminf(mn, __shfl_xor(mn, off));
            mx = fmaxf(mx, __shfl_xor(mx, off));
        }
        if (!lane) { red[wid] = mn; red[4 + wid] = mx; }
    }
    __syncthreads();
    mn = fminf(fminf(red[0], red[1]), fminf(red[2], red[3]));
    mx = fmaxf(fmaxf(red[4], red[5]), fmaxf(red[6], red[7]));
    float negM = -(a > 0.f ? a * mx : a * mn);   // exact row max (rank-1 logits)
    float zacc = 0.f;

    const unsigned short* gub = ub + (size_t)bh * 262144;

    f32x4 acc[8];
#pragma unroll
    for (int n = 0; n < 8; ++n) acc[n] = (f32x4)0.f;

#define DMA(icv, buf) do {                                                     \
    const unsigned short* src_ = gub + (size_t)((icv) >> 5) * 4096;            \
    _Pragma("unroll")                                                          \
    for (int q_ = 0; q_ < 2; ++q_) {                                           \
        int seg_ = q_ * 4 + wid;                                               \
        __builtin_amdgcn_global_load_lds(                                      \
            (const __attribute__((address_space(1))) unsigned int*)(src_ + seg_ * 512 + lane * 8), \
            (__attribute__((address_space(3))) unsigned int*)(&u_l[buf][seg_ * 512]),              \
            16, 0, 0);                                                         \
    }                                                                          \
} while (0)

    // prologue: 2 chunks in flight (4 DMA insts/wave outstanding)
    DMA(0, 0);
    DMA(32, 1);

    // main loop: chunks 0..62; chunk 63 handled in the tail (vmcnt(0))
#pragma unroll 3
    for (int ic = 0; ic < 2016; ic += 32) {
        int cn = ic >> 5;
        int cur = cn % 3;

        // per-lane P A-fragment: row = wid*16+l15, k = ic + l4*8 + j
        float4 ka = *(const float4*)&kss[ic + l4 * 8];
        float4 kb = *(const float4*)&kss[ic + l4 * 8 + 4];
        bf16x8 pf = pexp8s(ka, kb, a, negM, zacc);

        // wait: own chunk-cn DMAs done (leave chunk cn+1's 2 in flight)
        asm volatile("s_waitcnt vmcnt(2)" ::: "memory");
        __builtin_amdgcn_sched_barrier(0);
        __builtin_amdgcn_s_barrier();     // all waves' chunk-cn DMAs landed;
                                          // all reads of buf (cn-1)%3 done
        __builtin_amdgcn_sched_barrier(0);

        // refill the buffer read in iteration cn-1 with chunk cn+2
        if (cn + 2 <= 63) DMA(ic + 64, (cn + 2) % 3);
        __builtin_amdgcn_sched_barrier(0);

        __builtin_amdgcn_s_setprio(1);
#pragma unroll
        for (int n = 0; n < 8; ++n) {
            bf16x8 uf = *(const bf16x8*)&u_l[cur][n * 512 + lane * 8];
            acc[n] = __builtin_amdgcn_mfma_f32_16x16x32_bf16(pf, uf, acc[n], 0, 0, 0);
        }
        __builtin_amdgcn_s_setprio(0);
    }

    // tail: chunk 63 (buf 63%3 == 0), drain everything
    {
        float4 ka = *(const float4*)&kss[2016 + l4 * 8];
        float4 kb = *(const float4*)&kss[2016 + l4 * 8 + 4];
        bf16x8 pf = pexp8s(ka, kb, a, negM, zacc);
        asm volatile("s_waitcnt vmcnt(0)" ::: "memory");
        __builtin_amdgcn_sched_barrier(0);
        __builtin_amdgcn_s_barrier();
        __builtin_amdgcn_sched_barrier(0);
#pragma unroll
        for (int n = 0; n < 8; ++n) {
            bf16x8 uf = *(const bf16x8*)&u_l[0][n * 512 + lane * 8];
            acc[n] = __builtin_amdgcn_mfma_f32_16x16x32_bf16(pf, uf, acc[n], 0, 0, 0);
        }
    }
#undef DMA

    // z: sum the 4 k-groups (lanes with same l15) -> every lane has row-z
    zacc += __shfl_xor(zacc, 16);
    zacc += __shfl_xor(zacc, 32);
    __syncthreads();
    if (l4 == 0) zs[wid * 16 + l15] = zacc;
    __syncthreads();

    // epilogue: C/D layout col=lane&15, row=(lane>>4)*4+reg
#pragma unroll
    for (int r = 0; r < 4; ++r) {
        int tl = wid * 16 + l4 * 4 + r;
        float zinv = 1.f / zs[tl];
        float* yrow = y + ((size_t)b * 2048 + t0 + tl) * 128;
#pragma unroll
        for (int n = 0; n < 8; ++n)
            atomicAdd(&yrow[n * 16 + l15], acc[n][r] * zinv);
    }
}

extern "C" void kernel_launch(void* const* d_in, const int* in_sizes, int n_in,
                              void* d_out, int out_size, void* d_ws, size_t ws_size,
                              hipStream_t stream) {
    const float* x  = (const float*)d_in[0];
    const float* Wq = (const float*)d_in[1];
    const float* Wk = (const float*)d_in[2];
    const float* Wv = (const float*)d_in[3];
    const float* Wo = (const float*)d_in[4];
    const float* bo = (const float*)d_in[5];
    float* y  = (float*)d_out;
    float* ws = (float*)d_ws;
    (void)in_sizes; (void)n_in; (void)out_size; (void)ws_size;

    unsigned short* u16 = (unsigned short*)(ws + OFF_U);

    k_wsum<<<64, 256, 0, stream>>>(Wq, Wk, ws, bo, y);
    k_w2<<<1024, 128, 0, stream>>>(Wv, Wo, ws + OFF_W2);
    k_qsks<<<256, 256, 0, stream>>>(x, ws, ws + OFF_QS, ws + OFF_KS);
    k_ugemm<<<512, 256, 0, stream>>>(x, ws + OFF_W2, u16);
    k_attn<<<1024, 256, 0, stream>>>(ws + OFF_QS, ws + OFF_KS, u16, y);
}

// Round 11
// 97.757 us; speedup vs baseline: 1.2187x; 1.0861x over previous
//
#include <hip/hip_runtime.h>
#include <math.h>

// Problem constants
#define NB 4
#define NC 2048
#define NH 8
#define NK 128

// exp2-domain logit scale: log2(e)/sqrt(128)
#define A2SCALE (1.4426950408889634f * 0.08838834764831845f)

typedef __attribute__((ext_vector_type(8))) short bf16x8;
typedef __attribute__((ext_vector_type(4))) float f32x4;

// ---------------- ws layout (float offsets) ----------------
// wspart [4][2048]        @ 0        (8192)   e-quarter partials of wq/wk sums
// W2     [8][128][128]    @ 8192     (131072) f32
// qs     [32][2048]       @ 139264
// ks     [32][2048]       @ 204800
// u(bf16)[32][64ig][8nt][64lane][8j] @ 270336 (8.39M ushort)
#define OFF_W2  8192
#define OFF_QS  139264
#define OFF_KS  204800
#define OFF_U   270336

__device__ static inline float exp2_hw(float x) {
#if __has_builtin(__builtin_amdgcn_exp2f)
    return __builtin_amdgcn_exp2f(x);
#else
    float r;
    asm volatile("v_exp_f32 %0, %1\n\ts_nop 1" : "=v"(r) : "v"(x));
    return r;
#endif
}

// pack 2 f32 -> u32 of 2 bf16 (RNE), low half = first arg
__device__ static inline unsigned cvtpk(float lo, float hi) {
    unsigned r;
    asm("v_cvt_pk_bf16_f32 %0, %1, %2" : "=v"(r) : "v"(lo), "v"(hi));
    return r;
}

__device__ static inline bf16x8 pack8(float4 a, float4 b) {
    union { unsigned u[4]; bf16x8 v; } r;
    r.u[0] = cvtpk(a.x, a.y);
    r.u[1] = cvtpk(a.z, a.w);
    r.u[2] = cvtpk(b.x, b.y);
    r.u[3] = cvtpk(b.z, b.w);
    return r.v;
}

// 8 exps of (a*k + negM) packed to a bf16x8 A-fragment; accumulates sum in z
__device__ static inline bf16x8 pexp8s(float4 ka, float4 kb, float a, float negM,
                                       float& z) {
    float e0 = exp2_hw(fmaf(a, ka.x, negM));
    float e1 = exp2_hw(fmaf(a, ka.y, negM));
    float e2 = exp2_hw(fmaf(a, ka.z, negM));
    float e3 = exp2_hw(fmaf(a, ka.w, negM));
    float e4 = exp2_hw(fmaf(a, kb.x, negM));
    float e5 = exp2_hw(fmaf(a, kb.y, negM));
    float e6 = exp2_hw(fmaf(a, kb.z, negM));
    float e7 = exp2_hw(fmaf(a, kb.w, negM));
    z += ((e0 + e1) + (e2 + e3)) + ((e4 + e5) + (e6 + e7));
    union { unsigned u[4]; bf16x8 v; } r;
    r.u[0] = cvtpk(e0, e1);
    r.u[1] = cvtpk(e2, e3);
    r.u[2] = cvtpk(e4, e5);
    r.u[3] = cvtpk(e6, e7);
    return r.v;
}

// ---- prep1: (blk<64) wsum + y-bias-init ; (blk>=64) W2 ----  grid 576 x 256
// Bodies are the R10-proven k_wsum / R7-audited W2 branch.
__global__ __launch_bounds__(256) void k_prep1(const float* __restrict__ Wq,
                                               const float* __restrict__ Wk,
                                               const float* __restrict__ Wv,
                                               const float* __restrict__ Wo,
                                               const float* __restrict__ bo,
                                               float* __restrict__ wspart,
                                               float* __restrict__ W2,
                                               float* __restrict__ y) {
    int blk = blockIdx.x;
    int tid = threadIdx.x;
    __shared__ float sh[256];
    if (blk < 64) {
        int which = blk >> 5, h = (blk >> 2) & 7, eq = blk & 3;
        const float* W = which ? Wk : Wq;
        int m = tid & 127, part = tid >> 7;
        const float* base = W + (h * 128 + eq * 32 + part * 16) * 128 + m;
        float s = 0.f;
#pragma unroll
        for (int e = 0; e < 16; ++e) s += base[e * 128];
        if (part) sh[m] = s;
        __syncthreads();
        if (!part) wspart[eq * 2048 + which * 1024 + h * 128 + m] = s + sh[m];
        // y init: 262144 float4s over 64 blocks = 4096/block
        int base4 = blk * 4096 + tid;
#pragma unroll
        for (int q = 0; q < 16; ++q) {
            int id = base4 + q * 256;
            ((float4*)y)[id] = ((const float4*)bo)[id & 31];
        }
    } else {
        // W2[h][kk][m] = sum_e Wv[h*128+e][m] * Wo[kk][h*128+e]
        int idx = blk - 64;                    // 0..511
        int h = idx >> 6;
        int kl = tid >> 7;                     // 0..1
        int kk = (idx & 63) * 2 + kl;
        int m = tid & 127;
        float* wo_s = sh;                      // [2][128]
        wo_s[kl * 128 + m] = Wo[kk * 1024 + h * 128 + m];
        __syncthreads();
        const float* base = Wv + (h * 128) * 128 + m;
        const float* wrow = &wo_s[kl * 128];
        float s = 0.f;
#pragma unroll 4
        for (int e = 0; e < 128; ++e) s += base[e * 128] * wrow[e];
        W2[(h * 128 + kk) * 128 + m] = s;
    }
}

// ---- prep2: (blk<256) qs/ks ; (blk>=256) u-GEMM ----  grid 768 x 256
// Bodies are the R10-proven k_qsks / k_ugemm (XCD mapping kept: 256%8==0).
__global__ __launch_bounds__(256) void k_prep2(const float* __restrict__ x,
                                               const float* __restrict__ wspart,
                                               const float* __restrict__ W2,
                                               float* __restrict__ qs,
                                               float* __restrict__ ks,
                                               unsigned short* __restrict__ u16) {
    __shared__ __align__(16) unsigned char smem_u8[32768];
    int tid = threadIdx.x;
    int blk = blockIdx.x;
    if (blk < 256) {
        float* xs = (float*)smem_u8;              // [32][129]
        float* wsum = (float*)smem_u8 + 32 * 129; // [2048]
        for (int j = tid; j < 2048; j += 256)
            wsum[j] = wspart[j] + wspart[2048 + j] + wspart[4096 + j] + wspart[6144 + j];
        int row0 = blk * 32;
        for (int j = tid; j < 32 * 128; j += 256) {
            int r = j >> 7, m = j & 127;
            xs[r * 129 + m] = x[(size_t)(row0 + r) * 128 + m];
        }
        __syncthreads();
#pragma unroll
        for (int jj = 0; jj < 2; ++jj) {
            int o = tid + 256 * jj;
            int r = o & 31;
            int q = o >> 5;
            int which = q >> 3, h = q & 7;
            const float* wrow = &wsum[which * 1024 + h * 128];
            const float* xrow = &xs[r * 129];
            float s = 0.f;
#pragma unroll 4
            for (int m = 0; m < 128; ++m) s += xrow[m] * wrow[m];
            int row = row0 + r, b = row >> 11, t = row & 2047;
            float* dst = which ? ks : qs;
            dst[(b * 8 + h) * 2048 + t] = s;
        }
    } else {
        int gid = blk - 256;                  // HW XCD of this block = gid%8
        int xcd = gid & 7, s = gid >> 3;      // s in 0..63
        int bh = xcd * 4 + (s >> 4);          // bh>>2 == xcd (matches k_attn)
        int it = s & 15;
        int b = bh >> 3, h = bh & 7;
        int lane = tid & 63, wid = tid >> 6;
        int wr = wid >> 1, wc = wid & 1;
        int l15 = lane & 15, l4 = lane >> 4;

        const float* xb = x + (size_t)(b * 2048 + it * 128) * 128;
        const float* w2h = W2 + h * 16384;

        f32x4 acc[4][4];
#pragma unroll
        for (int m = 0; m < 4; ++m)
#pragma unroll
            for (int n = 0; n < 4; ++n) acc[m][n] = (f32x4)0.f;

#pragma unroll
        for (int mg = 0; mg < 4; ++mg) {
            bf16x8 af[4], bfr[4];
#pragma unroll
            for (int m = 0; m < 4; ++m) {
                const float* src = xb + (wr * 64 + m * 16 + l15) * 128 + mg * 32 + l4 * 8;
                af[m] = pack8(*(const float4*)src, *(const float4*)(src + 4));
            }
#pragma unroll
            for (int n = 0; n < 4; ++n) {
                const float* src = w2h + (wc * 64 + n * 16 + l15) * 128 + mg * 32 + l4 * 8;
                bfr[n] = pack8(*(const float4*)src, *(const float4*)(src + 4));
            }
#pragma unroll
            for (int m = 0; m < 4; ++m)
#pragma unroll
                for (int n = 0; n < 4; ++n)
                    acc[m][n] = __builtin_amdgcn_mfma_f32_16x16x32_bf16(
                        af[m], bfr[n], acc[m][n], 0, 0, 0);
        }

        // transpose acc -> u B-frag layout through LDS (32 KB)
        unsigned* u_sh = (unsigned*)smem_u8;
#pragma unroll
        for (int m = 0; m < 4; ++m) {
            int i_base = wr * 64 + m * 16 + l4 * 4;
            int ig = i_base >> 5;
            int lg = 16 * ((i_base >> 3) & 3);
            int jp = (i_base & 7) >> 1;          // 0 or 2
#pragma unroll
            for (int n = 0; n < 4; ++n) {
                int kk = wc * 64 + n * 16 + l15;
                int lp = (kk & 15) + lg;
                int idx = ((ig * 8 + (kk >> 4)) * 64 + lp) * 4 + jp;
                uint2 w;
                w.x = cvtpk(acc[m][n][0], acc[m][n][1]);
                w.y = cvtpk(acc[m][n][2], acc[m][n][3]);
                *(uint2*)&u_sh[idx] = w;
            }
        }
        __syncthreads();
        unsigned short* ub = u16 + ((size_t)(b * 8 + h) * 64 + it * 4) * 4096;
#pragma unroll
        for (int q = 0; q < 8; ++q)
            ((uint4*)ub)[tid + q * 256] = ((const uint4*)u_sh)[tid + q * 256];
    }
}

// ---- attention: y[b][t][kk] += (1/z_t) sum_i P[t,i] * u[i,kk] ----
// grid 512 x 256: 32 bh x 16 t-tiles of 128. 4 waves x 32 rows x 128 kk
// (m=2 groups, n=8). CHUNK = 64 i (half the barriers of R10), 3 x 16 KB LDS
// buffers, counted s_waitcnt vmcnt(4) (4 DMA insts/wave/chunk; chunk n+1
// stays in flight across the barrier). Loop has NO other VMEM -> counts exact.
__global__ __launch_bounds__(256, 2) void k_attn(const float* __restrict__ qs,
                                                 const float* __restrict__ ks,
                                                 const unsigned short* __restrict__ ub,
                                                 float* __restrict__ y) {
    int L = blockIdx.x;
    int xcd = L & 7, slot = L >> 3;
    int bh = xcd * 4 + (slot >> 4);   // 4 bh per XCD
    int tt = slot & 15;
    int b = bh >> 3;
    int t0 = tt * 128;
    int tid = threadIdx.x;
    int lane = tid & 63, wid = tid >> 6;
    int l15 = lane & 15, l4 = lane >> 4;

    __shared__ float kss[2048];                           // 8 KB
    __shared__ __align__(16) unsigned short u_l[3][8192]; // 3 x 16 KB
    __shared__ float zs[128];
    __shared__ float red[8];

    for (int j = tid; j < 512; j += 256)
        ((float4*)kss)[j] = ((const float4*)(ks + bh * 2048))[j];
    // this lane's rows: t0 + wid*32 + mg*16 + l15, mg = 0..1
    float a[2], negM[2], z[2];
#pragma unroll
    for (int mg = 0; mg < 2; ++mg)
        a[mg] = qs[bh * 2048 + t0 + wid * 32 + mg * 16 + l15] * A2SCALE;
    __syncthreads();

    // block-wide min/max of kss
    float mn = 1e30f, mx = -1e30f;
    {
        const float4* ka = (const float4*)kss;
#pragma unroll
        for (int jj = 0; jj < 2; ++jj) {
            float4 v = ka[tid + jj * 256];
            mn = fminf(mn, fminf(fminf(v.x, v.y), fminf(v.z, v.w)));
            mx = fmaxf(mx, fmaxf(fmaxf(v.x, v.y), fmaxf(v.z, v.w)));
        }
#pragma unroll
        for (int off = 32; off; off >>= 1) {
            mn = fminf(mn, __shfl_xor(mn, off));
            mx = fmaxf(mx, __shfl_xor(mx, off));
        }
        if (!lane) { red[wid] = mn; red[4 + wid] = mx; }
    }
    __syncthreads();
    mn = fminf(fminf(red[0], red[1]), fminf(red[2], red[3]));
    mx = fmaxf(fmaxf(red[4], red[5]), fmaxf(red[6], red[7]));
#pragma unroll
    for (int mg = 0; mg < 2; ++mg) {
        negM[mg] = -(a[mg] > 0.f ? a[mg] * mx : a[mg] * mn);   // exact row max
        z[mg] = 0.f;
    }

    const unsigned short* gub = ub + (size_t)bh * 262144;

    f32x4 acc[2][8];
#pragma unroll
    for (int mg = 0; mg < 2; ++mg)
#pragma unroll
        for (int n = 0; n < 8; ++n) acc[mg][n] = (f32x4)0.f;

// chunk = 64 i = 16 KB; per wave 4 DMA insts (1 KB each)
#define DMA(chv, buf) do {                                                     \
    const unsigned short* src_ = gub + (size_t)(chv) * 8192;                   \
    _Pragma("unroll")                                                          \
    for (int q_ = 0; q_ < 4; ++q_) {                                           \
        int seg_ = q_ * 4 + wid;                                               \
        __builtin_amdgcn_global_load_lds(                                      \
            (const __attribute__((address_space(1))) unsigned int*)(src_ + seg_ * 512 + lane * 8), \
            (__attribute__((address_space(3))) unsigned int*)(&u_l[buf][seg_ * 512]),              \
            16, 0, 0);                                                         \
    }                                                                          \
} while (0)

    // prologue: chunks 0,1 in flight (8 insts/wave outstanding)
    DMA(0, 0);
    DMA(1, 1);

    // main loop: chunks 0..30; chunk 31 in the tail (vmcnt(0))
    for (int cn = 0; cn < 31; ++cn) {
        int ic = cn * 64;
        int cur = cn % 3;

        // per-lane P A-fragments: row = wid*32+mg*16+l15, k = ic+kq*32+l4*8+j
        bf16x8 pf[2][2];
#pragma unroll
        for (int kq = 0; kq < 2; ++kq) {
            float4 ka = *(const float4*)&kss[ic + kq * 32 + l4 * 8];
            float4 kb = *(const float4*)&kss[ic + kq * 32 + l4 * 8 + 4];
            pf[0][kq] = pexp8s(ka, kb, a[0], negM[0], z[0]);
            pf[1][kq] = pexp8s(ka, kb, a[1], negM[1], z[1]);
        }

        // wait: chunk cn landed (leave chunk cn+1's 4 insts in flight)
        asm volatile("s_waitcnt vmcnt(4)" ::: "memory");
        __builtin_amdgcn_sched_barrier(0);
        __builtin_amdgcn_s_barrier();     // + all reads of buf (cn-1)%3 done
        __builtin_amdgcn_sched_barrier(0);

        // refill the buffer read in iteration cn-1 with chunk cn+2
        if (cn + 2 <= 31) DMA(cn + 2, (cn + 2) % 3);
        __builtin_amdgcn_sched_barrier(0);

        __builtin_amdgcn_s_setprio(1);
#pragma unroll
        for (int kq = 0; kq < 2; ++kq) {
#pragma unroll
            for (int n = 0; n < 8; ++n) {
                bf16x8 uf = *(const bf16x8*)&u_l[cur][(kq * 8 + n) * 512 + lane * 8];
                acc[0][n] = __builtin_amdgcn_mfma_f32_16x16x32_bf16(
                    pf[0][kq], uf, acc[0][n], 0, 0, 0);
                acc[1][n] = __builtin_amdgcn_mfma_f32_16x16x32_bf16(
                    pf[1][kq], uf, acc[1][n], 0, 0, 0);
            }
        }
        __builtin_amdgcn_s_setprio(0);
    }

    // tail: chunk 31 (buf 31%3 == 1), drain everything
    {
        int ic = 31 * 64;
        bf16x8 pf[2][2];
#pragma unroll
        for (int kq = 0; kq < 2; ++kq) {
            float4 ka = *(const float4*)&kss[ic + kq * 32 + l4 * 8];
            float4 kb = *(const float4*)&kss[ic + kq * 32 + l4 * 8 + 4];
            pf[0][kq] = pexp8s(ka, kb, a[0], negM[0], z[0]);
            pf[1][kq] = pexp8s(ka, kb, a[1], negM[1], z[1]);
        }
        asm volatile("s_waitcnt vmcnt(0)" ::: "memory");
        __builtin_amdgcn_sched_barrier(0);
        __builtin_amdgcn_s_barrier();
        __builtin_amdgcn_sched_barrier(0);
#pragma unroll
        for (int kq = 0; kq < 2; ++kq) {
#pragma unroll
            for (int n = 0; n < 8; ++n) {
                bf16x8 uf = *(const bf16x8*)&u_l[1][(kq * 8 + n) * 512 + lane * 8];
                acc[0][n] = __builtin_amdgcn_mfma_f32_16x16x32_bf16(
                    pf[0][kq], uf, acc[0][n], 0, 0, 0);
                acc[1][n] = __builtin_amdgcn_mfma_f32_16x16x32_bf16(
                    pf[1][kq], uf, acc[1][n], 0, 0, 0);
            }
        }
    }
#undef DMA

    // z: sum the 4 k-groups (over l4) -> lanes with same l15 share row-z
#pragma unroll
    for (int mg = 0; mg < 2; ++mg) {
        z[mg] += __shfl_xor(z[mg], 16);
        z[mg] += __shfl_xor(z[mg], 32);
    }
    __syncthreads();
    if (l4 == 0) {
#pragma unroll
        for (int mg = 0; mg < 2; ++mg) zs[wid * 32 + mg * 16 + l15] = z[mg];
    }
    __syncthreads();

    // epilogue: C/D layout col=lane&15, row=(lane>>4)*4+reg
#pragma unroll
    for (int mg = 0; mg < 2; ++mg) {
#pragma unroll
        for (int r = 0; r < 4; ++r) {
            int tl = wid * 32 + mg * 16 + l4 * 4 + r;
            float zinv = 1.f / zs[tl];
            float* yrow = y + ((size_t)b * 2048 + t0 + tl) * 128;
#pragma unroll
            for (int n = 0; n < 8; ++n)
                atomicAdd(&yrow[n * 16 + l15], acc[mg][n][r] * zinv);
        }
    }
}

extern "C" void kernel_launch(void* const* d_in, const int* in_sizes, int n_in,
                              void* d_out, int out_size, void* d_ws, size_t ws_size,
                              hipStream_t stream) {
    const float* x  = (const float*)d_in[0];
    const float* Wq = (const float*)d_in[1];
    const float* Wk = (const float*)d_in[2];
    const float* Wv = (const float*)d_in[3];
    const float* Wo = (const float*)d_in[4];
    const float* bo = (const float*)d_in[5];
    float* y  = (float*)d_out;
    float* ws = (float*)d_ws;
    (void)in_sizes; (void)n_in; (void)out_size; (void)ws_size;

    unsigned short* u16 = (unsigned short*)(ws + OFF_U);

    k_prep1<<<576, 256, 0, stream>>>(Wq, Wk, Wv, Wo, bo, ws, ws + OFF_W2, y);
    k_prep2<<<768, 256, 0, stream>>>(x, ws, ws + OFF_W2, ws + OFF_QS, ws + OFF_KS, u16);
    k_attn<<<512, 256, 0, stream>>>(ws + OFF_QS, ws + OFF_KS, u16, y);
}